// Round 1
// baseline (531.430 us; speedup 1.0000x reference)
//
#include <hip/hip_runtime.h>
#include <hip/hip_bf16.h>
#include <hip/hip_cooperative_groups.h>

namespace cg = cooperative_groups;

// Sizes (fixed): B=1, D=H=W=16 -> L=4096, C=96, d=96, K=6, N=16, R=6
#define L 4096
#define CDIM 96
#define DDIM 96
#define KDIR 6
#define NST 16
#define RRK 6
#define YH 32        // Y2h row: B at [0..15], C at [16..31] (half)
#define NCHUNK 256
#define CHLEN 16     // NCHUNK*CHLEN == L
#define GRIDN 512    // cooperative grid: 2 blocks/CU * 256 CUs

typedef _Float16 half4v __attribute__((ext_vector_type(4)));

__device__ __forceinline__ float sigmoidf_(float x) { return 1.f / (1.f + __expf(-x)); }

// scan-position l -> spatial index s for base direction kb in {0,1,2}
__device__ __forceinline__ int sigma_k(int kb, int l) {
    if (kb == 0) return l;
    if (kb == 1) return ((l & 15) << 8) | ((l >> 8) << 4) | ((l >> 4) & 15);
    return (((l >> 4) & 15) << 8) | ((l & 15) << 4) | (l >> 8);
}

// ============================================================================
// Fused persistent cooperative kernel: all 7 phases, 6 grid syncs.
// 512 blocks x 256 threads, 2 blocks/CU guaranteed by __launch_bounds__(256,2).
// ============================================================================
__global__ void __launch_bounds__(256, 2) fused_vss(
        const float* __restrict__ x, const float* __restrict__ ln1_w,
        const float* __restrict__ ln1_b, const float* __restrict__ in_proj,
        const float* __restrict__ conv_w, const float* __restrict__ conv_b,
        const float* __restrict__ x_proj, const float* __restrict__ dt_w,
        const float* __restrict__ dt_b, const float* __restrict__ A_log,
        const float* __restrict__ D_skip, const float* __restrict__ onw,
        const float* __restrict__ onb, const float* __restrict__ out_w,
        float* __restrict__ out,
        _Float16* __restrict__ xhh, _Float16* __restrict__ zsh,
        _Float16* __restrict__ xch, _Float16* __restrict__ xcTh,
        _Float16* __restrict__ Y2h, _Float16* __restrict__ Zsh,
        _Float16* __restrict__ ysh, _Float16* __restrict__ Aah,
        _Float16* __restrict__ Abh, _Float16* __restrict__ Pbh) {
    cg::grid_group grid = cg::this_grid();
    const int tid = threadIdx.x;
    const int bid = blockIdx.x;
    const int G = gridDim.x;

    __shared__ __align__(16) float smA[8][96];
    __shared__ __align__(16) float smB[8][96];
    __shared__ float sms[8], smr[8];
    __shared__ float dts[256][6];

    // -------- P1: LN + in_proj (was k1, 192 active threads of 256) --------
    for (int u = bid; u < L / 8; u += G) {
        int s0 = u * 8;
        if (tid < 192)
            ((float4*)&smA[0][0])[tid] = ((const float4*)(x + (size_t)s0 * 96))[tid];
        __syncthreads();
        int wave = tid >> 6, lane = tid & 63;
        for (int r = wave; r < 8; r += 4) {
            float v = smA[r][lane] + ((lane < 32) ? smA[r][64 + lane] : 0.f);
#pragma unroll
            for (int off = 1; off < 64; off <<= 1) v += __shfl_xor(v, off);
            float vs = smA[r][lane] * smA[r][lane] + ((lane < 32) ? smA[r][64 + lane] * smA[r][64 + lane] : 0.f);
#pragma unroll
            for (int off = 1; off < 64; off <<= 1) vs += __shfl_xor(vs, off);
            if (lane == 0) {
                float mean = v * (1.f / 96.f);
                float var = vs * (1.f / 96.f) - mean * mean;
                sms[r] = mean; smr[r] = rsqrtf(var + 1e-6f);
            }
        }
        __syncthreads();
        if (tid < 192) {
            int r = tid / 24, c4 = tid % 24;
            float4 xv = ((float4*)&smA[r][0])[c4];
            float4 wv = ((const float4*)ln1_w)[c4];
            float4 bv = ((const float4*)ln1_b)[c4];
            float m = sms[r], rs = smr[r];
            float4 o;
            o.x = (xv.x - m) * rs * wv.x + bv.x;
            o.y = (xv.y - m) * rs * wv.y + bv.y;
            o.z = (xv.z - m) * rs * wv.z + bv.z;
            o.w = (xv.w - m) * rs * wv.w + bv.w;
            ((float4*)&smB[r][0])[c4] = o;
        }
        float4 Wr[24];
        if (tid < 192) {
            const float4* wr = (const float4*)(in_proj + (size_t)tid * 96);
#pragma unroll
            for (int c4 = 0; c4 < 24; c4++) Wr[c4] = wr[c4];
        }
        __syncthreads();
        if (tid < 192) {
#pragma unroll
            for (int s = 0; s < 8; s++) {
                const float4* xr4 = (const float4*)&smB[s][0];
                float a0 = 0.f, a1 = 0.f, a2 = 0.f, a3 = 0.f;
#pragma unroll
                for (int c4 = 0; c4 < 24; c4 += 4) {
                    float4 x0 = xr4[c4], x1 = xr4[c4 + 1], x2 = xr4[c4 + 2], x3 = xr4[c4 + 3];
                    a0 += Wr[c4].x * x0.x + Wr[c4].y * x0.y + Wr[c4].z * x0.z + Wr[c4].w * x0.w;
                    a1 += Wr[c4+1].x * x1.x + Wr[c4+1].y * x1.y + Wr[c4+1].z * x1.z + Wr[c4+1].w * x1.w;
                    a2 += Wr[c4+2].x * x2.x + Wr[c4+2].y * x2.y + Wr[c4+2].z * x2.z + Wr[c4+2].w * x2.w;
                    a3 += Wr[c4+3].x * x3.x + Wr[c4+3].y * x3.y + Wr[c4+3].z * x3.z + Wr[c4+3].w * x3.w;
                }
                float acc = (a0 + a1) + (a2 + a3);
                if (tid < 96) xhh[(size_t)tid * L + s0 + s] = (_Float16)acc;
                else zsh[(size_t)(s0 + s) * 96 + (tid - 96)] = (_Float16)(acc * sigmoidf_(acc));
            }
        }
        __syncthreads();
    }
    grid.sync();

    // -------- P2: depthwise conv 3x3x3 + SiLU (was k2) --------
    for (int u = bid; u < (96 * L) / 256; u += G) {
        int idx = u * 256 + tid;
        int c = idx >> 12, s = idx & 4095;
        int dz = s >> 8, h = (s >> 4) & 15, w = s & 15;
        const _Float16* xin = xhh + (size_t)c * L;
        const float* wc = conv_w + c * 27;
        float acc = conv_b[c];
#pragma unroll
        for (int i = 0; i < 3; i++) {
            int z2 = dz + i - 1; if ((unsigned)z2 > 15u) continue;
#pragma unroll
            for (int j = 0; j < 3; j++) {
                int h2 = h + j - 1; if ((unsigned)h2 > 15u) continue;
#pragma unroll
                for (int kk = 0; kk < 3; kk++) {
                    int w2 = w + kk - 1; if ((unsigned)w2 > 15u) continue;
                    acc += (float)xin[z2 * 256 + h2 * 16 + w2] * wc[i * 9 + j * 3 + kk];
                }
            }
        }
        float r = acc * sigmoidf_(acc);
        _Float16 hr = (_Float16)r;
        xch[(size_t)c * L + s] = hr;
        xcTh[(size_t)s * 96 + c] = hr;
    }
    grid.sync();

    // -------- P3: x_proj + dt expand + softplus (was k3) --------
    for (int u = bid; u < 384; u += G) {
        int k = u % 6;
        int sb = (u / 6) % 16;
        int g = u / 96;
        int sbase = sb * 256;
        int s = sbase + tid;
        float acc[14];
#pragma unroll
        for (int i = 0; i < 14; i++) acc[i] = 0.f;
        const float* wdt_rows = x_proj + (size_t)k * 38 * DDIM;
        const float* wbc      = x_proj + ((size_t)k * 38 + 6 + g * 8) * DDIM;
        for (int dd = 0; dd < 96; dd += 4) {
            float v[4];
#pragma unroll
            for (int j = 0; j < 4; j++) v[j] = (float)xch[(size_t)(dd + j) * L + s];
#pragma unroll
            for (int j = 0; j < 4; j++) {
#pragma unroll
                for (int r = 0; r < 6; r++) acc[r] += wdt_rows[r * DDIM + dd + j] * v[j];
#pragma unroll
                for (int i = 0; i < 8; i++) acc[6 + i] += wbc[i * DDIM + dd + j] * v[j];
            }
        }
        _Float16* yo = Y2h + ((size_t)k * L + s) * YH;
#pragma unroll
        for (int i = 0; i < 8; i++) yo[g * 8 + i] = (_Float16)acc[6 + i];
#pragma unroll
        for (int r = 0; r < 6; r++) dts[tid][r] = acc[r];
        __syncthreads();
        for (int i = 0; i < 24; i++) {
            int idx = i * 256 + tid;
            int dl = idx % 24;
            int sr = idx / 24;
            int d = g * 24 + dl;
            const float* wr = dt_w + ((size_t)k * 96 + d) * 6;
            float a = dt_b[k * 96 + d];
#pragma unroll
            for (int r = 0; r < 6; r++) a += wr[r] * dts[sr][r];
            float sp = (a > 15.f) ? a : __logf(1.f + __expf(a));
            Zsh[((size_t)k * L + sbase + sr) * 96 + d] = (_Float16)sp;
        }
        __syncthreads();
    }
    grid.sync();

    // -------- PA: chunk-local scan (was ka_scan) --------
    for (int u = bid; u < KDIR * NCHUNK * DDIM * 4 / 256; u += G) {
        int t = u * 256 + tid;
        int nq = t & 3;
        int q = t >> 2;
        int d = q % 96;
        int rest = q / 96;
        int chunk = rest % NCHUNK;
        int k = rest / NCHUNK;
        int kb = (k < 3) ? k : (k - 3);
        bool flip = (k >= 3);
        float An[4];
        {
            float4 al = *(const float4*)(A_log + ((size_t)k * 96 + d) * 16 + nq * 4);
            An[0] = -__expf(al.x); An[1] = -__expf(al.y);
            An[2] = -__expf(al.z); An[3] = -__expf(al.w);
        }
        float a[4] = {1.f, 1.f, 1.f, 1.f};
        float b[4] = {0.f, 0.f, 0.f, 0.f};
        const _Float16* Zk = Zsh + (size_t)k * L * 96;
        const _Float16* Yk = Y2h + (size_t)k * L * YH;
        int l0 = chunk * CHLEN;
        for (int i = 0; i < CHLEN; i += 4) {
            int sI[4]; float dt[4], xv[4]; half4v Bh[4];
#pragma unroll
            for (int j = 0; j < 4; j++) {
                int l = l0 + i + j;
                int lp = flip ? (4095 - l) : l;
                sI[j] = sigma_k(kb, lp);
            }
#pragma unroll
            for (int j = 0; j < 4; j++) {
                dt[j] = (float)Zk[(size_t)sI[j] * 96 + d];
                xv[j] = (float)xcTh[(size_t)sI[j] * 96 + d];
                Bh[j] = *(const half4v*)(Yk + (size_t)sI[j] * YH + nq * 4);
            }
#pragma unroll
            for (int j = 0; j < 4; j++) {
                float dtx = dt[j] * xv[j];
                float e0 = __expf(dt[j] * An[0]);
                float e1 = __expf(dt[j] * An[1]);
                float e2 = __expf(dt[j] * An[2]);
                float e3 = __expf(dt[j] * An[3]);
                b[0] = e0 * b[0] + dtx * (float)Bh[j].x; a[0] *= e0;
                b[1] = e1 * b[1] + dtx * (float)Bh[j].y; a[1] *= e1;
                b[2] = e2 * b[2] + dtx * (float)Bh[j].z; a[2] *= e2;
                b[3] = e3 * b[3] + dtx * (float)Bh[j].w; a[3] *= e3;
            }
        }
        size_t o = (((size_t)k * NCHUNK + chunk) * 96 + d) * 16 + nq * 4;
        half4v ha, hb;
        ha.x = (_Float16)a[0]; ha.y = (_Float16)a[1]; ha.z = (_Float16)a[2]; ha.w = (_Float16)a[3];
        hb.x = (_Float16)b[0]; hb.y = (_Float16)b[1]; hb.z = (_Float16)b[2]; hb.w = (_Float16)b[3];
        *(half4v*)(Aah + o) = ha;
        *(half4v*)(Abh + o) = hb;
    }
    grid.sync();

    // -------- PB: serial combine across chunks (was kb_combine) --------
    for (int u = bid; u < KDIR * DDIM * NST / 256; u += G) {
        int t = u * 256 + tid;
        int n = t & 15;
        int rest = t >> 4;
        int d = rest % 96;
        int k = rest / 96;
        size_t base = ((size_t)k * NCHUNK * 96 + d) * 16 + n;
        const size_t cstride = 96 * 16;
        float rb = 0.f;
        for (int c0 = 0; c0 < NCHUNK; c0 += 16) {
            float av[16], bv[16];
#pragma unroll
            for (int j = 0; j < 16; j++) {
                av[j] = (float)Aah[base + (size_t)(c0 + j) * cstride];
                bv[j] = (float)Abh[base + (size_t)(c0 + j) * cstride];
            }
#pragma unroll
            for (int j = 0; j < 16; j++) {
                Pbh[base + (size_t)(c0 + j) * cstride] = (_Float16)rb;
                rb = av[j] * rb + bv[j];
            }
        }
    }
    grid.sync();

    // -------- PC: re-scan + apply C + D skip (was kc_apply) --------
    for (int u = bid; u < KDIR * NCHUNK * DDIM * 4 / 256; u += G) {
        int t = u * 256 + tid;
        int nq = t & 3;
        int q = t >> 2;
        int d = q % 96;
        int rest = q / 96;
        int chunk = rest % NCHUNK;
        int k = rest / NCHUNK;
        int kb = (k < 3) ? k : (k - 3);
        bool flip = (k >= 3);
        float An[4];
        {
            float4 al = *(const float4*)(A_log + ((size_t)k * 96 + d) * 16 + nq * 4);
            An[0] = -__expf(al.x); An[1] = -__expf(al.y);
            An[2] = -__expf(al.z); An[3] = -__expf(al.w);
        }
        float Dk = D_skip[k * DDIM + d];
        float h[4];
        {
            half4v hp = *(const half4v*)(Pbh + (((size_t)k * NCHUNK + chunk) * 96 + d) * 16 + nq * 4);
            h[0] = (float)hp.x; h[1] = (float)hp.y; h[2] = (float)hp.z; h[3] = (float)hp.w;
        }
        const _Float16* Zk = Zsh + (size_t)k * L * 96;
        const _Float16* Yk = Y2h + (size_t)k * L * YH;
        int l0 = chunk * CHLEN;
        for (int i = 0; i < CHLEN; i += 4) {
            int sI[4]; float dt[4], xv[4]; half4v Bh[4], Ch[4];
#pragma unroll
            for (int j = 0; j < 4; j++) {
                int l = l0 + i + j;
                int lp = flip ? (4095 - l) : l;
                sI[j] = sigma_k(kb, lp);
            }
#pragma unroll
            for (int j = 0; j < 4; j++) {
                dt[j] = (float)Zk[(size_t)sI[j] * 96 + d];
                xv[j] = (float)xcTh[(size_t)sI[j] * 96 + d];
                Bh[j] = *(const half4v*)(Yk + (size_t)sI[j] * YH + nq * 4);
                Ch[j] = *(const half4v*)(Yk + (size_t)sI[j] * YH + 16 + nq * 4);
            }
#pragma unroll
            for (int j = 0; j < 4; j++) {
                float dtx = dt[j] * xv[j];
                float e0 = __expf(dt[j] * An[0]);
                float e1 = __expf(dt[j] * An[1]);
                float e2 = __expf(dt[j] * An[2]);
                float e3 = __expf(dt[j] * An[3]);
                h[0] = e0 * h[0] + dtx * (float)Bh[j].x;
                h[1] = e1 * h[1] + dtx * (float)Bh[j].y;
                h[2] = e2 * h[2] + dtx * (float)Bh[j].z;
                h[3] = e3 * h[3] + dtx * (float)Bh[j].w;
                float p = h[0] * (float)Ch[j].x + h[1] * (float)Ch[j].y
                        + h[2] * (float)Ch[j].z + h[3] * (float)Ch[j].w;
                p += __shfl_xor(p, 1);
                p += __shfl_xor(p, 2);
                if (nq == 0) ysh[((size_t)sI[j] * KDIR + k) * 96 + d] = (_Float16)(p + Dk * xv[j]);
            }
        }
    }
    grid.sync();

    // -------- P6: k-sum + out LN + z gate + out_proj + residual (was k6) --------
    for (int u = bid; u < L / 8; u += G) {
        int s0 = u * 8;
#pragma unroll
        for (int j = 0; j < 3; j++) {
            int f = tid + j * 256;               // < 768
            int sr = f / 96, c = f % 96;
            const _Float16* yr = ysh + ((size_t)(s0 + sr) * KDIR) * 96 + c;
            float v = 0.f;
#pragma unroll
            for (int k = 0; k < KDIR; k++) v += (float)yr[k * 96];
            smA[sr][c] = v;
        }
        __syncthreads();
        int wave = tid >> 6, lane = tid & 63;
        for (int r = wave; r < 8; r += 4) {
            float v = smA[r][lane] + ((lane < 32) ? smA[r][64 + lane] : 0.f);
#pragma unroll
            for (int off = 1; off < 64; off <<= 1) v += __shfl_xor(v, off);
            float vs = smA[r][lane] * smA[r][lane] + ((lane < 32) ? smA[r][64 + lane] * smA[r][64 + lane] : 0.f);
#pragma unroll
            for (int off = 1; off < 64; off <<= 1) vs += __shfl_xor(vs, off);
            if (lane == 0) {
                float mean = v * (1.f / 96.f);
                float var = vs * (1.f / 96.f) - mean * mean;
                sms[r] = mean; smr[r] = rsqrtf(var + 1e-5f);
            }
        }
        __syncthreads();
#pragma unroll
        for (int j = 0; j < 3; j++) {
            int f = tid + j * 256;
            int sr = f / 96, c = f % 96;
            float g = (smA[sr][c] - sms[sr]) * smr[sr] * onw[c] + onb[c];
            smB[sr][c] = g * (float)zsh[(size_t)(s0 + sr) * 96 + c];
        }
        float4 Wr[24];
        if (tid < 192) {
            int e = tid % 96;
            const float4* wr = (const float4*)(out_w + (size_t)e * 96);
#pragma unroll
            for (int c4 = 0; c4 < 24; c4++) Wr[c4] = wr[c4];
        }
        __syncthreads();
        if (tid < 192) {
            int e = tid % 96, sg = tid / 96;     // sg in {0,1}
#pragma unroll
            for (int j = 0; j < 4; j++) {
                int s = sg * 4 + j;
                const float4* g4 = (const float4*)&smB[s][0];
                float a0 = 0.f, a1 = 0.f, a2 = 0.f, a3 = 0.f;
#pragma unroll
                for (int c4 = 0; c4 < 24; c4 += 4) {
                    float4 x0 = g4[c4], x1 = g4[c4 + 1], x2 = g4[c4 + 2], x3 = g4[c4 + 3];
                    a0 += Wr[c4].x * x0.x + Wr[c4].y * x0.y + Wr[c4].z * x0.z + Wr[c4].w * x0.w;
                    a1 += Wr[c4+1].x * x1.x + Wr[c4+1].y * x1.y + Wr[c4+1].z * x1.z + Wr[c4+1].w * x1.w;
                    a2 += Wr[c4+2].x * x2.x + Wr[c4+2].y * x2.y + Wr[c4+2].z * x2.z + Wr[c4+2].w * x2.w;
                    a3 += Wr[c4+3].x * x3.x + Wr[c4+3].y * x3.y + Wr[c4+3].z * x3.z + Wr[c4+3].w * x3.w;
                }
                float acc = (a0 + a1) + (a2 + a3) + x[(size_t)(s0 + s) * 96 + e];
                out[(size_t)(s0 + s) * 96 + e] = acc;
            }
        }
        __syncthreads();
    }
}

// ============================================================================
// Fallback path: the previous verified 7-kernel pipeline (unchanged).
// ============================================================================

__global__ void __launch_bounds__(192) k1_ln_inproj(
        const float* __restrict__ x, const float* __restrict__ ln_w,
        const float* __restrict__ ln_b, const float* __restrict__ Wp,
        _Float16* __restrict__ xhh, _Float16* __restrict__ zsh) {
    int s0 = blockIdx.x * 8;
    int tid = threadIdx.x;
    __shared__ __align__(16) float xt[8][96];
    __shared__ __align__(16) float xn[8][96];
    __shared__ float mss[8], rss[8];
    ((float4*)&xt[0][0])[tid] = ((const float4*)(x + (size_t)s0 * 96))[tid];
    __syncthreads();
    int wave = tid >> 6, lane = tid & 63;
    for (int r = wave; r < 8; r += 3) {
        float v = xt[r][lane] + ((lane < 32) ? xt[r][64 + lane] : 0.f);
#pragma unroll
        for (int off = 1; off < 64; off <<= 1) v += __shfl_xor(v, off);
        float vs = xt[r][lane] * xt[r][lane] + ((lane < 32) ? xt[r][64 + lane] * xt[r][64 + lane] : 0.f);
#pragma unroll
        for (int off = 1; off < 64; off <<= 1) vs += __shfl_xor(vs, off);
        if (lane == 0) {
            float mean = v * (1.f / 96.f);
            float var = vs * (1.f / 96.f) - mean * mean;
            mss[r] = mean; rss[r] = rsqrtf(var + 1e-6f);
        }
    }
    __syncthreads();
    {
        int r = tid / 24, c4 = tid % 24;
        float4 xv = ((float4*)&xt[r][0])[c4];
        float4 wv = ((const float4*)ln_w)[c4];
        float4 bv = ((const float4*)ln_b)[c4];
        float m = mss[r], rs = rss[r];
        float4 o;
        o.x = (xv.x - m) * rs * wv.x + bv.x;
        o.y = (xv.y - m) * rs * wv.y + bv.y;
        o.z = (xv.z - m) * rs * wv.z + bv.z;
        o.w = (xv.w - m) * rs * wv.w + bv.w;
        ((float4*)&xn[r][0])[c4] = o;
    }
    float4 Wr[24];
    const float4* wr = (const float4*)(Wp + (size_t)tid * 96);
#pragma unroll
    for (int c4 = 0; c4 < 24; c4++) Wr[c4] = wr[c4];
    __syncthreads();
#pragma unroll
    for (int s = 0; s < 8; s++) {
        const float4* xr4 = (const float4*)&xn[s][0];
        float a0 = 0.f, a1 = 0.f, a2 = 0.f, a3 = 0.f;
#pragma unroll
        for (int c4 = 0; c4 < 24; c4 += 4) {
            float4 x0 = xr4[c4], x1 = xr4[c4 + 1], x2 = xr4[c4 + 2], x3 = xr4[c4 + 3];
            a0 += Wr[c4].x * x0.x + Wr[c4].y * x0.y + Wr[c4].z * x0.z + Wr[c4].w * x0.w;
            a1 += Wr[c4+1].x * x1.x + Wr[c4+1].y * x1.y + Wr[c4+1].z * x1.z + Wr[c4+1].w * x1.w;
            a2 += Wr[c4+2].x * x2.x + Wr[c4+2].y * x2.y + Wr[c4+2].z * x2.z + Wr[c4+2].w * x2.w;
            a3 += Wr[c4+3].x * x3.x + Wr[c4+3].y * x3.y + Wr[c4+3].z * x3.z + Wr[c4+3].w * x3.w;
        }
        float acc = (a0 + a1) + (a2 + a3);
        if (tid < 96) xhh[(size_t)tid * L + s0 + s] = (_Float16)acc;
        else zsh[(size_t)(s0 + s) * 96 + (tid - 96)] = (_Float16)(acc * sigmoidf_(acc));
    }
}

__global__ void k2_conv(const _Float16* __restrict__ xhh, const float* __restrict__ cw,
                        const float* __restrict__ cb, _Float16* __restrict__ xch,
                        _Float16* __restrict__ xcTh) {
    int idx = blockIdx.x * 256 + threadIdx.x;
    int c = idx >> 12, s = idx & 4095;
    int dz = s >> 8, h = (s >> 4) & 15, w = s & 15;
    const _Float16* xin = xhh + (size_t)c * L;
    const float* wc = cw + c * 27;
    float acc = cb[c];
#pragma unroll
    for (int i = 0; i < 3; i++) {
        int z2 = dz + i - 1; if ((unsigned)z2 > 15u) continue;
#pragma unroll
        for (int j = 0; j < 3; j++) {
            int h2 = h + j - 1; if ((unsigned)h2 > 15u) continue;
#pragma unroll
            for (int kk = 0; kk < 3; kk++) {
                int w2 = w + kk - 1; if ((unsigned)w2 > 15u) continue;
                acc += (float)xin[z2 * 256 + h2 * 16 + w2] * wc[i * 9 + j * 3 + kk];
            }
        }
    }
    float r = acc * sigmoidf_(acc);
    _Float16 hr = (_Float16)r;
    xch[(size_t)c * L + s] = hr;
    xcTh[(size_t)s * 96 + c] = hr;
}

__global__ void k3_xproj(const _Float16* __restrict__ xch, const float* __restrict__ Wx,
                         const float* __restrict__ Wdt, const float* __restrict__ bdt,
                         _Float16* __restrict__ Y2h, _Float16* __restrict__ Zsh) {
    int k = blockIdx.x;
    int tid = threadIdx.x;
    int sbase = blockIdx.y * 256;
    int s = sbase + tid;
    int g = blockIdx.z;
    __shared__ float dts[256][6];
    float acc[14];
#pragma unroll
    for (int i = 0; i < 14; i++) acc[i] = 0.f;
    const float* wdt_rows = Wx + (size_t)k * 38 * DDIM;
    const float* wbc      = Wx + ((size_t)k * 38 + 6 + g * 8) * DDIM;
    for (int dd = 0; dd < 96; dd += 4) {
        float v[4];
#pragma unroll
        for (int j = 0; j < 4; j++) v[j] = (float)xch[(size_t)(dd + j) * L + s];
#pragma unroll
        for (int j = 0; j < 4; j++) {
#pragma unroll
            for (int r = 0; r < 6; r++) acc[r] += wdt_rows[r * DDIM + dd + j] * v[j];
#pragma unroll
            for (int i = 0; i < 8; i++) acc[6 + i] += wbc[i * DDIM + dd + j] * v[j];
        }
    }
    _Float16* yo = Y2h + ((size_t)k * L + s) * YH;
#pragma unroll
    for (int i = 0; i < 8; i++) yo[g * 8 + i] = (_Float16)acc[6 + i];
#pragma unroll
    for (int r = 0; r < 6; r++) dts[tid][r] = acc[r];
    __syncthreads();
    for (int i = 0; i < 24; i++) {
        int idx = i * 256 + tid;
        int dl = idx % 24;
        int sr = idx / 24;
        int d = g * 24 + dl;
        const float* wr = Wdt + ((size_t)k * 96 + d) * 6;
        float a = bdt[k * 96 + d];
#pragma unroll
        for (int r = 0; r < 6; r++) a += wr[r] * dts[sr][r];
        float sp = (a > 15.f) ? a : __logf(1.f + __expf(a));
        Zsh[((size_t)k * L + sbase + sr) * 96 + d] = (_Float16)sp;
    }
}

__global__ void __launch_bounds__(256) ka_scan(
        const _Float16* __restrict__ Zsh, const _Float16* __restrict__ xcTh,
        const _Float16* __restrict__ Y2h, const float* __restrict__ A_log,
        _Float16* __restrict__ Aah, _Float16* __restrict__ Abh) {
    int t = blockIdx.x * 256 + threadIdx.x;
    int nq = t & 3;
    int q = t >> 2;
    int d = q % 96;
    int rest = q / 96;
    int chunk = rest % NCHUNK;
    int k = rest / NCHUNK;
    int kb = (k < 3) ? k : (k - 3);
    bool flip = (k >= 3);
    float An[4];
    {
        float4 al = *(const float4*)(A_log + ((size_t)k * 96 + d) * 16 + nq * 4);
        An[0] = -__expf(al.x); An[1] = -__expf(al.y);
        An[2] = -__expf(al.z); An[3] = -__expf(al.w);
    }
    float a[4] = {1.f, 1.f, 1.f, 1.f};
    float b[4] = {0.f, 0.f, 0.f, 0.f};
    const _Float16* Zk = Zsh + (size_t)k * L * 96;
    const _Float16* Yk = Y2h + (size_t)k * L * YH;
    int l0 = chunk * CHLEN;
    for (int i = 0; i < CHLEN; i += 4) {
        int sI[4]; float dt[4], xv[4]; half4v Bh[4];
#pragma unroll
        for (int j = 0; j < 4; j++) {
            int l = l0 + i + j;
            int lp = flip ? (4095 - l) : l;
            sI[j] = sigma_k(kb, lp);
        }
#pragma unroll
        for (int j = 0; j < 4; j++) {
            dt[j] = (float)Zk[(size_t)sI[j] * 96 + d];
            xv[j] = (float)xcTh[(size_t)sI[j] * 96 + d];
            Bh[j] = *(const half4v*)(Yk + (size_t)sI[j] * YH + nq * 4);
        }
#pragma unroll
        for (int j = 0; j < 4; j++) {
            float dtx = dt[j] * xv[j];
            float e0 = __expf(dt[j] * An[0]);
            float e1 = __expf(dt[j] * An[1]);
            float e2 = __expf(dt[j] * An[2]);
            float e3 = __expf(dt[j] * An[3]);
            b[0] = e0 * b[0] + dtx * (float)Bh[j].x; a[0] *= e0;
            b[1] = e1 * b[1] + dtx * (float)Bh[j].y; a[1] *= e1;
            b[2] = e2 * b[2] + dtx * (float)Bh[j].z; a[2] *= e2;
            b[3] = e3 * b[3] + dtx * (float)Bh[j].w; a[3] *= e3;
        }
    }
    size_t o = (((size_t)k * NCHUNK + chunk) * 96 + d) * 16 + nq * 4;
    half4v ha, hb;
    ha.x = (_Float16)a[0]; ha.y = (_Float16)a[1]; ha.z = (_Float16)a[2]; ha.w = (_Float16)a[3];
    hb.x = (_Float16)b[0]; hb.y = (_Float16)b[1]; hb.z = (_Float16)b[2]; hb.w = (_Float16)b[3];
    *(half4v*)(Aah + o) = ha;
    *(half4v*)(Abh + o) = hb;
}

__global__ void __launch_bounds__(256) kb_combine(
        const _Float16* __restrict__ Aah, const _Float16* __restrict__ Abh,
        _Float16* __restrict__ Pbh) {
    int t = blockIdx.x * 256 + threadIdx.x;
    int n = t & 15;
    int rest = t >> 4;
    int d = rest % 96;
    int k = rest / 96;
    size_t base = ((size_t)k * NCHUNK * 96 + d) * 16 + n;
    const size_t cstride = 96 * 16;
    float rb = 0.f;
    for (int c0 = 0; c0 < NCHUNK; c0 += 16) {
        float av[16], bv[16];
#pragma unroll
        for (int j = 0; j < 16; j++) {
            av[j] = (float)Aah[base + (size_t)(c0 + j) * cstride];
            bv[j] = (float)Abh[base + (size_t)(c0 + j) * cstride];
        }
#pragma unroll
        for (int j = 0; j < 16; j++) {
            Pbh[base + (size_t)(c0 + j) * cstride] = (_Float16)rb;
            rb = av[j] * rb + bv[j];
        }
    }
}

__global__ void __launch_bounds__(256) kc_apply(
        const _Float16* __restrict__ Zsh, const _Float16* __restrict__ xcTh,
        const _Float16* __restrict__ Y2h, const float* __restrict__ A_log,
        const float* __restrict__ D_skip, const _Float16* __restrict__ Pbh,
        _Float16* __restrict__ ysh) {
    int t = blockIdx.x * 256 + threadIdx.x;
    int nq = t & 3;
    int q = t >> 2;
    int d = q % 96;
    int rest = q / 96;
    int chunk = rest % NCHUNK;
    int k = rest / NCHUNK;
    int kb = (k < 3) ? k : (k - 3);
    bool flip = (k >= 3);
    float An[4];
    {
        float4 al = *(const float4*)(A_log + ((size_t)k * 96 + d) * 16 + nq * 4);
        An[0] = -__expf(al.x); An[1] = -__expf(al.y);
        An[2] = -__expf(al.z); An[3] = -__expf(al.w);
    }
    float Dk = D_skip[k * DDIM + d];
    float h[4];
    {
        half4v hp = *(const half4v*)(Pbh + (((size_t)k * NCHUNK + chunk) * 96 + d) * 16 + nq * 4);
        h[0] = (float)hp.x; h[1] = (float)hp.y; h[2] = (float)hp.z; h[3] = (float)hp.w;
    }
    const _Float16* Zk = Zsh + (size_t)k * L * 96;
    const _Float16* Yk = Y2h + (size_t)k * L * YH;
    int l0 = chunk * CHLEN;
    for (int i = 0; i < CHLEN; i += 4) {
        int sI[4]; float dt[4], xv[4]; half4v Bh[4], Ch[4];
#pragma unroll
        for (int j = 0; j < 4; j++) {
            int l = l0 + i + j;
            int lp = flip ? (4095 - l) : l;
            sI[j] = sigma_k(kb, lp);
        }
#pragma unroll
        for (int j = 0; j < 4; j++) {
            dt[j] = (float)Zk[(size_t)sI[j] * 96 + d];
            xv[j] = (float)xcTh[(size_t)sI[j] * 96 + d];
            Bh[j] = *(const half4v*)(Yk + (size_t)sI[j] * YH + nq * 4);
            Ch[j] = *(const half4v*)(Yk + (size_t)sI[j] * YH + 16 + nq * 4);
        }
#pragma unroll
        for (int j = 0; j < 4; j++) {
            float dtx = dt[j] * xv[j];
            float e0 = __expf(dt[j] * An[0]);
            float e1 = __expf(dt[j] * An[1]);
            float e2 = __expf(dt[j] * An[2]);
            float e3 = __expf(dt[j] * An[3]);
            h[0] = e0 * h[0] + dtx * (float)Bh[j].x;
            h[1] = e1 * h[1] + dtx * (float)Bh[j].y;
            h[2] = e2 * h[2] + dtx * (float)Bh[j].z;
            h[3] = e3 * h[3] + dtx * (float)Bh[j].w;
            float p = h[0] * (float)Ch[j].x + h[1] * (float)Ch[j].y
                    + h[2] * (float)Ch[j].z + h[3] * (float)Ch[j].w;
            p += __shfl_xor(p, 1);
            p += __shfl_xor(p, 2);
            if (nq == 0) ysh[((size_t)sI[j] * KDIR + k) * 96 + d] = (_Float16)(p + Dk * xv[j]);
        }
    }
}

__global__ void __launch_bounds__(192) k6_out(
        const _Float16* __restrict__ ysh, const _Float16* __restrict__ zsh,
        const float* __restrict__ onw, const float* __restrict__ onb,
        const float* __restrict__ Wo, const float* __restrict__ x,
        float* __restrict__ out) {
    int s0 = blockIdx.x * 8;
    int tid = threadIdx.x;
    __shared__ __align__(16) float vt[8][96];
    __shared__ __align__(16) float gt[8][96];
    __shared__ float mss[8], rss[8];
#pragma unroll
    for (int j = 0; j < 4; j++) {
        int f = tid + j * 192;
        int sr = f / 96, c = f % 96;
        const _Float16* yr = ysh + ((size_t)(s0 + sr) * KDIR) * 96 + c;
        float v = 0.f;
#pragma unroll
        for (int k = 0; k < KDIR; k++) v += (float)yr[k * 96];
        vt[sr][c] = v;
    }
    __syncthreads();
    int wave = tid >> 6, lane = tid & 63;
    for (int r = wave; r < 8; r += 3) {
        float v = vt[r][lane] + ((lane < 32) ? vt[r][64 + lane] : 0.f);
#pragma unroll
        for (int off = 1; off < 64; off <<= 1) v += __shfl_xor(v, off);
        float vs = vt[r][lane] * vt[r][lane] + ((lane < 32) ? vt[r][64 + lane] * vt[r][64 + lane] : 0.f);
#pragma unroll
        for (int off = 1; off < 64; off <<= 1) vs += __shfl_xor(vs, off);
        if (lane == 0) {
            float mean = v * (1.f / 96.f);
            float var = vs * (1.f / 96.f) - mean * mean;
            mss[r] = mean; rss[r] = rsqrtf(var + 1e-5f);
        }
    }
    __syncthreads();
#pragma unroll
    for (int j = 0; j < 4; j++) {
        int f = tid + j * 192;
        int sr = f / 96, c = f % 96;
        float g = (vt[sr][c] - mss[sr]) * rss[sr] * onw[c] + onb[c];
        gt[sr][c] = g * (float)zsh[(size_t)(s0 + sr) * 96 + c];
    }
    int e = tid % 96, sg = tid / 96;
    float4 Wr[24];
    const float4* wr = (const float4*)(Wo + (size_t)e * 96);
#pragma unroll
    for (int c4 = 0; c4 < 24; c4++) Wr[c4] = wr[c4];
    __syncthreads();
#pragma unroll
    for (int j = 0; j < 4; j++) {
        int s = sg * 4 + j;
        const float4* g4 = (const float4*)&gt[s][0];
        float a0 = 0.f, a1 = 0.f, a2 = 0.f, a3 = 0.f;
#pragma unroll
        for (int c4 = 0; c4 < 24; c4 += 4) {
            float4 x0 = g4[c4], x1 = g4[c4 + 1], x2 = g4[c4 + 2], x3 = g4[c4 + 3];
            a0 += Wr[c4].x * x0.x + Wr[c4].y * x0.y + Wr[c4].z * x0.z + Wr[c4].w * x0.w;
            a1 += Wr[c4+1].x * x1.x + Wr[c4+1].y * x1.y + Wr[c4+1].z * x1.z + Wr[c4+1].w * x1.w;
            a2 += Wr[c4+2].x * x2.x + Wr[c4+2].y * x2.y + Wr[c4+2].z * x2.z + Wr[c4+2].w * x2.w;
            a3 += Wr[c4+3].x * x3.x + Wr[c4+3].y * x3.y + Wr[c4+3].z * x3.z + Wr[c4+3].w * x3.w;
        }
        float acc = (a0 + a1) + (a2 + a3) + x[(size_t)(s0 + s) * 96 + e];
        out[(size_t)(s0 + s) * 96 + e] = acc;
    }
}

extern "C" void kernel_launch(void* const* d_in, const int* in_sizes, int n_in,
                              void* d_out, int out_size, void* d_ws, size_t ws_size,
                              hipStream_t stream) {
    const float* x        = (const float*)d_in[0];
    const float* ln1_w    = (const float*)d_in[1];
    const float* ln1_b    = (const float*)d_in[2];
    const float* in_proj  = (const float*)d_in[3];
    const float* conv_w   = (const float*)d_in[4];
    const float* conv_b   = (const float*)d_in[5];
    const float* x_proj   = (const float*)d_in[6];
    const float* dt_w     = (const float*)d_in[7];
    const float* dt_b     = (const float*)d_in[8];
    const float* A_log    = (const float*)d_in[9];
    const float* D_skip   = (const float*)d_in[10];
    const float* onw      = (const float*)d_in[11];
    const float* onb      = (const float*)d_in[12];
    const float* out_w    = (const float*)d_in[13];
    float* out = (float*)d_out;

    _Float16* xhh  = (_Float16*)d_ws;                 // 96*4096
    _Float16* zsh  = xhh + (size_t)96 * L;            // 4096*96
    _Float16* xch  = zsh + (size_t)96 * L;            // 96*4096
    _Float16* xcTh = xch + (size_t)96 * L;            // 4096*96
    _Float16* Y2h  = xcTh + (size_t)96 * L;           // 6*4096*32
    _Float16* Zsh  = Y2h + (size_t)KDIR * L * YH;     // 6*4096*96
    _Float16* ysh  = Zsh + (size_t)KDIR * L * 96;     // 4096*6*96
    _Float16* Aah  = ysh + (size_t)L * KDIR * 96;     // 6*256*96*16
    _Float16* Abh  = Aah + (size_t)KDIR * NCHUNK * DDIM * NST;
    _Float16* Pbh  = Abh + (size_t)KDIR * NCHUNK * DDIM * NST;

    void* args[] = {
        (void*)&x, (void*)&ln1_w, (void*)&ln1_b, (void*)&in_proj,
        (void*)&conv_w, (void*)&conv_b, (void*)&x_proj, (void*)&dt_w,
        (void*)&dt_b, (void*)&A_log, (void*)&D_skip, (void*)&onw,
        (void*)&onb, (void*)&out_w, (void*)&out,
        (void*)&xhh, (void*)&zsh, (void*)&xch, (void*)&xcTh, (void*)&Y2h,
        (void*)&Zsh, (void*)&ysh, (void*)&Aah, (void*)&Abh, (void*)&Pbh
    };
    hipError_t err = hipLaunchCooperativeKernel(fused_vss, dim3(GRIDN), dim3(256),
                                                args, 0u, stream);
    if (err != hipSuccess) {
        (void)hipGetLastError();  // clear sticky error; fall back to 7-kernel path
        k1_ln_inproj<<<dim3(L / 8), dim3(192), 0, stream>>>(x, ln1_w, ln1_b, in_proj, xhh, zsh);
        k2_conv<<<dim3(96 * L / 256), dim3(256), 0, stream>>>(xhh, conv_w, conv_b, xch, xcTh);
        k3_xproj<<<dim3(KDIR, 16, 4), dim3(256), 0, stream>>>(xch, x_proj, dt_w, dt_b, Y2h, Zsh);
        ka_scan<<<dim3(KDIR * NCHUNK * DDIM * 4 / 256), dim3(256), 0, stream>>>(Zsh, xcTh, Y2h, A_log, Aah, Abh);
        kb_combine<<<dim3(KDIR * DDIM * NST / 256), dim3(256), 0, stream>>>(Aah, Abh, Pbh);
        kc_apply<<<dim3(KDIR * NCHUNK * DDIM * 4 / 256), dim3(256), 0, stream>>>(Zsh, xcTh, Y2h, A_log, D_skip, Pbh, ysh);
        k6_out<<<dim3(L / 8), dim3(192), 0, stream>>>(ysh, zsh, onw, onb, out_w, x, out);
    }
}

// Round 2
// 210.232 us; speedup vs baseline: 2.5278x; 2.5278x over previous
//
#include <hip/hip_runtime.h>
#include <hip/hip_bf16.h>

// Sizes (fixed): B=1, D=H=W=16 -> L=4096, C=96, d=96, K=6, N=16, R=6
#define L 4096
#define CDIM 96
#define DDIM 96
#define KDIR 6
#define NST 16
#define RRK 6
#define YH 32        // Y2h row: B at [0..15], C at [16..31] (half)
#define SCHUNK 64    // chunks per (k,d) in merged scan
#define SCLEN 64     // elements per chunk (SCHUNK*SCLEN == L)

typedef _Float16 half4v __attribute__((ext_vector_type(4)));

__device__ __forceinline__ float sigmoidf_(float x) { return 1.f / (1.f + __expf(-x)); }

// scan-position l -> spatial index s for base direction kb in {0,1,2}
__device__ __forceinline__ int sigma_k(int kb, int l) {
    if (kb == 0) return l;
    if (kb == 1) return ((l & 15) << 8) | ((l >> 8) << 4) | ((l >> 4) & 15);
    return (((l >> 4) & 15) << 8) | ((l & 15) << 4) | (l >> 8);
}

// K1: LN + in_proj, weight-in-registers, 8 spatial rows per block.
__global__ void __launch_bounds__(192) k1_ln_inproj(
        const float* __restrict__ x, const float* __restrict__ ln_w,
        const float* __restrict__ ln_b, const float* __restrict__ Wp,
        _Float16* __restrict__ xhh, _Float16* __restrict__ zsh) {
    int s0 = blockIdx.x * 8;
    int tid = threadIdx.x;
    __shared__ __align__(16) float xt[8][96];
    __shared__ __align__(16) float xn[8][96];
    __shared__ float mss[8], rss[8];
    ((float4*)&xt[0][0])[tid] = ((const float4*)(x + (size_t)s0 * 96))[tid];
    __syncthreads();
    int wave = tid >> 6, lane = tid & 63;
    for (int r = wave; r < 8; r += 3) {
        float v = xt[r][lane] + ((lane < 32) ? xt[r][64 + lane] : 0.f);
#pragma unroll
        for (int off = 1; off < 64; off <<= 1) v += __shfl_xor(v, off);
        float vs = xt[r][lane] * xt[r][lane] + ((lane < 32) ? xt[r][64 + lane] * xt[r][64 + lane] : 0.f);
#pragma unroll
        for (int off = 1; off < 64; off <<= 1) vs += __shfl_xor(vs, off);
        if (lane == 0) {
            float mean = v * (1.f / 96.f);
            float var = vs * (1.f / 96.f) - mean * mean;
            mss[r] = mean; rss[r] = rsqrtf(var + 1e-6f);
        }
    }
    __syncthreads();
    {
        int r = tid / 24, c4 = tid % 24;
        float4 xv = ((float4*)&xt[r][0])[c4];
        float4 wv = ((const float4*)ln_w)[c4];
        float4 bv = ((const float4*)ln_b)[c4];
        float m = mss[r], rs = rss[r];
        float4 o;
        o.x = (xv.x - m) * rs * wv.x + bv.x;
        o.y = (xv.y - m) * rs * wv.y + bv.y;
        o.z = (xv.z - m) * rs * wv.z + bv.z;
        o.w = (xv.w - m) * rs * wv.w + bv.w;
        ((float4*)&xn[r][0])[c4] = o;
    }
    float4 Wr[24];
    const float4* wr = (const float4*)(Wp + (size_t)tid * 96);
#pragma unroll
    for (int c4 = 0; c4 < 24; c4++) Wr[c4] = wr[c4];
    __syncthreads();
#pragma unroll
    for (int s = 0; s < 8; s++) {
        const float4* xr4 = (const float4*)&xn[s][0];
        float a0 = 0.f, a1 = 0.f, a2 = 0.f, a3 = 0.f;
#pragma unroll
        for (int c4 = 0; c4 < 24; c4 += 4) {
            float4 x0 = xr4[c4], x1 = xr4[c4 + 1], x2 = xr4[c4 + 2], x3 = xr4[c4 + 3];
            a0 += Wr[c4].x * x0.x + Wr[c4].y * x0.y + Wr[c4].z * x0.z + Wr[c4].w * x0.w;
            a1 += Wr[c4+1].x * x1.x + Wr[c4+1].y * x1.y + Wr[c4+1].z * x1.z + Wr[c4+1].w * x1.w;
            a2 += Wr[c4+2].x * x2.x + Wr[c4+2].y * x2.y + Wr[c4+2].z * x2.z + Wr[c4+2].w * x2.w;
            a3 += Wr[c4+3].x * x3.x + Wr[c4+3].y * x3.y + Wr[c4+3].z * x3.z + Wr[c4+3].w * x3.w;
        }
        float acc = (a0 + a1) + (a2 + a3);
        if (tid < 96) xhh[(size_t)tid * L + s0 + s] = (_Float16)acc;
        else zsh[(size_t)(s0 + s) * 96 + (tid - 96)] = (_Float16)(acc * sigmoidf_(acc));
    }
}

// K2: depthwise 3x3x3 conv (SAME) + bias + SiLU; writes xch[c][s] and xcTh[s][c]
__global__ void k2_conv(const _Float16* __restrict__ xhh, const float* __restrict__ cw,
                        const float* __restrict__ cb, _Float16* __restrict__ xch,
                        _Float16* __restrict__ xcTh) {
    int idx = blockIdx.x * 256 + threadIdx.x; // 96*4096
    int c = idx >> 12, s = idx & 4095;
    int dz = s >> 8, h = (s >> 4) & 15, w = s & 15;
    const _Float16* xin = xhh + (size_t)c * L;
    const float* wc = cw + c * 27;
    float acc = cb[c];
#pragma unroll
    for (int i = 0; i < 3; i++) {
        int z2 = dz + i - 1; if ((unsigned)z2 > 15u) continue;
#pragma unroll
        for (int j = 0; j < 3; j++) {
            int h2 = h + j - 1; if ((unsigned)h2 > 15u) continue;
#pragma unroll
            for (int kk = 0; kk < 3; kk++) {
                int w2 = w + kk - 1; if ((unsigned)w2 > 15u) continue;
                acc += (float)xin[z2 * 256 + h2 * 16 + w2] * wc[i * 9 + j * 3 + kk];
            }
        }
    }
    float r = acc * sigmoidf_(acc);
    _Float16 hr = (_Float16)r;
    xch[(size_t)c * L + s] = hr;
    xcTh[(size_t)s * 96 + c] = hr;
}

// K3 (+fused K4, balanced): grid (6,16,4). Group g computes the 6 dt channels
// (redundantly) + 8 B/C channels, then expands dt -> Zsh for its 24-of-96 d-range.
__global__ void k3_xproj(const _Float16* __restrict__ xch, const float* __restrict__ Wx,
                         const float* __restrict__ Wdt, const float* __restrict__ bdt,
                         _Float16* __restrict__ Y2h, _Float16* __restrict__ Zsh) {
    int k = blockIdx.x;
    int tid = threadIdx.x;
    int sbase = blockIdx.y * 256;
    int s = sbase + tid;
    int g = blockIdx.z;   // 0..3
    __shared__ float dts[256][6];
    float acc[14];
#pragma unroll
    for (int i = 0; i < 14; i++) acc[i] = 0.f;
    const float* wdt_rows = Wx + (size_t)k * 38 * DDIM;                 // channels 0..5
    const float* wbc      = Wx + ((size_t)k * 38 + 6 + g * 8) * DDIM;   // 8 B/C channels
    for (int dd = 0; dd < 96; dd += 4) {
        float v[4];
#pragma unroll
        for (int j = 0; j < 4; j++) v[j] = (float)xch[(size_t)(dd + j) * L + s];
#pragma unroll
        for (int j = 0; j < 4; j++) {
#pragma unroll
            for (int r = 0; r < 6; r++) acc[r] += wdt_rows[r * DDIM + dd + j] * v[j];
#pragma unroll
            for (int i = 0; i < 8; i++) acc[6 + i] += wbc[i * DDIM + dd + j] * v[j];
        }
    }
    _Float16* yo = Y2h + ((size_t)k * L + s) * YH;
#pragma unroll
    for (int i = 0; i < 8; i++) yo[g * 8 + i] = (_Float16)acc[6 + i];
#pragma unroll
    for (int r = 0; r < 6; r++) dts[tid][r] = acc[r];
    __syncthreads();
    for (int i = 0; i < 24; i++) {
        int idx = i * 256 + tid;      // < 6144 = 256 sr * 24 dl
        int dl = idx % 24;
        int sr = idx / 24;
        int d = g * 24 + dl;
        const float* wr = Wdt + ((size_t)k * 96 + d) * 6;
        float a = bdt[k * 96 + d];
#pragma unroll
        for (int r = 0; r < 6; r++) a += wr[r] * dts[sr][r];
        float sp = (a > 15.f) ? a : __logf(1.f + __expf(a));
        Zsh[((size_t)k * L + sbase + sr) * 96 + d] = (_Float16)sp;
    }
}

// KSCAN: merged ka+kb+kc. One block per (k,d). 256 threads = 64 chunks x 4 nq.
// Each thread: 4 states (nq*4..nq*4+3), chunk of SCLEN=64 scan positions.
// Pass A: chunk-local (a,b). LDS Hillis-Steele across 64 chunks (fp32).
// Pass C: re-scan with carry, fuse y = sum_n h*C + D*x.
__global__ void __launch_bounds__(256) kscan(
        const _Float16* __restrict__ Zsh, const _Float16* __restrict__ xcTh,
        const _Float16* __restrict__ Y2h, const float* __restrict__ A_log,
        const float* __restrict__ D_skip, _Float16* __restrict__ ysh) {
    int blk = blockIdx.x;           // 0..575
    int k = blk / 96, d = blk % 96;
    int tid = threadIdx.x;
    int nq = tid & 3;
    int chunk = tid >> 2;           // 0..63
    int kb = (k < 3) ? k : (k - 3);
    bool flip = (k >= 3);

    __shared__ float lds_a[SCHUNK][16];
    __shared__ float lds_b[SCHUNK][16];

    float An[4];
    {
        float4 al = *(const float4*)(A_log + ((size_t)k * 96 + d) * 16 + nq * 4);
        // pre-scale by log2(e): exp(dt*A) == exp2(dt*(A*log2e)); exp2f is native v_exp
        An[0] = -__expf(al.x) * 1.44269504f; An[1] = -__expf(al.y) * 1.44269504f;
        An[2] = -__expf(al.z) * 1.44269504f; An[3] = -__expf(al.w) * 1.44269504f;
    }
    const _Float16* Zk = Zsh + (size_t)k * L * 96;
    const _Float16* Yk = Y2h + (size_t)k * L * YH;
    int l0 = chunk * SCLEN;

    // ---- Pass A: chunk-local scan ----
    float a[4] = {1.f, 1.f, 1.f, 1.f};
    float b[4] = {0.f, 0.f, 0.f, 0.f};
    for (int i = 0; i < SCLEN; i += 4) {
        int sI[4]; float dt[4], xv[4]; half4v Bh[4];
#pragma unroll
        for (int j = 0; j < 4; j++) {
            int l = l0 + i + j;
            int lp = flip ? (4095 - l) : l;
            sI[j] = sigma_k(kb, lp);
        }
#pragma unroll
        for (int j = 0; j < 4; j++) {
            dt[j] = (float)Zk[(size_t)sI[j] * 96 + d];
            xv[j] = (float)xcTh[(size_t)sI[j] * 96 + d];
            Bh[j] = *(const half4v*)(Yk + (size_t)sI[j] * YH + nq * 4);
        }
#pragma unroll
        for (int j = 0; j < 4; j++) {
            float dtx = dt[j] * xv[j];
            float e0 = exp2f(dt[j] * An[0]);
            float e1 = exp2f(dt[j] * An[1]);
            float e2 = exp2f(dt[j] * An[2]);
            float e3 = exp2f(dt[j] * An[3]);
            b[0] = e0 * b[0] + dtx * (float)Bh[j].x; a[0] *= e0;
            b[1] = e1 * b[1] + dtx * (float)Bh[j].y; a[1] *= e1;
            b[2] = e2 * b[2] + dtx * (float)Bh[j].z; a[2] *= e2;
            b[3] = e3 * b[3] + dtx * (float)Bh[j].w; a[3] *= e3;
        }
    }
#pragma unroll
    for (int i = 0; i < 4; i++) {
        lds_a[chunk][nq * 4 + i] = a[i];
        lds_b[chunk][nq * 4 + i] = b[i];
    }
    __syncthreads();

    // ---- Block-level inclusive scan across 64 chunks, 16 states ----
    // combine(prev, cur) = (cur.a*prev.a, cur.a*prev.b + cur.b)
    for (int off = 1; off < SCHUNK; off <<= 1) {
        float na[4], nb[4]; int cc[4], st[4]; bool act[4];
#pragma unroll
        for (int j = 0; j < 4; j++) {
            int idx = tid + j * 256;        // < 1024 = 64 chunks * 16 states
            int c = idx >> 4, s2 = idx & 15;
            cc[j] = c; st[j] = s2;
            act[j] = (c >= off);
            if (act[j]) {
                float pa = lds_a[c - off][s2], pb = lds_b[c - off][s2];
                float ca = lds_a[c][s2],       cb = lds_b[c][s2];
                na[j] = ca * pa;
                nb[j] = ca * pb + cb;
            }
        }
        __syncthreads();
#pragma unroll
        for (int j = 0; j < 4; j++) {
            if (act[j]) { lds_a[cc[j]][st[j]] = na[j]; lds_b[cc[j]][st[j]] = nb[j]; }
        }
        __syncthreads();
    }

    // carry into this chunk = inclusive of chunk-1 (0 for chunk 0)
    float h[4];
#pragma unroll
    for (int i = 0; i < 4; i++)
        h[i] = (chunk == 0) ? 0.f : lds_b[chunk - 1][nq * 4 + i];
    float Dk = D_skip[k * DDIM + d];

    // ---- Pass C: re-scan with carry, apply C and D skip ----
    for (int i = 0; i < SCLEN; i += 4) {
        int sI[4]; float dt[4], xv[4]; half4v Bh[4], Ch[4];
#pragma unroll
        for (int j = 0; j < 4; j++) {
            int l = l0 + i + j;
            int lp = flip ? (4095 - l) : l;
            sI[j] = sigma_k(kb, lp);
        }
#pragma unroll
        for (int j = 0; j < 4; j++) {
            dt[j] = (float)Zk[(size_t)sI[j] * 96 + d];
            xv[j] = (float)xcTh[(size_t)sI[j] * 96 + d];
            Bh[j] = *(const half4v*)(Yk + (size_t)sI[j] * YH + nq * 4);
            Ch[j] = *(const half4v*)(Yk + (size_t)sI[j] * YH + 16 + nq * 4);
        }
#pragma unroll
        for (int j = 0; j < 4; j++) {
            float dtx = dt[j] * xv[j];
            float e0 = exp2f(dt[j] * An[0]);
            float e1 = exp2f(dt[j] * An[1]);
            float e2 = exp2f(dt[j] * An[2]);
            float e3 = exp2f(dt[j] * An[3]);
            h[0] = e0 * h[0] + dtx * (float)Bh[j].x;
            h[1] = e1 * h[1] + dtx * (float)Bh[j].y;
            h[2] = e2 * h[2] + dtx * (float)Bh[j].z;
            h[3] = e3 * h[3] + dtx * (float)Bh[j].w;
            float p = h[0] * (float)Ch[j].x + h[1] * (float)Ch[j].y
                    + h[2] * (float)Ch[j].z + h[3] * (float)Ch[j].w;
            p += __shfl_xor(p, 1);
            p += __shfl_xor(p, 2);
            if (nq == 0) ysh[((size_t)sI[j] * KDIR + k) * 96 + d] = (_Float16)(p + Dk * xv[j]);
        }
    }
}

// K6: weight-in-registers out stage. 8 s-rows per block, 192 thr, grid 512.
__global__ void __launch_bounds__(192) k6_out(
        const _Float16* __restrict__ ysh, const _Float16* __restrict__ zsh,
        const float* __restrict__ onw, const float* __restrict__ onb,
        const float* __restrict__ Wo, const float* __restrict__ x,
        float* __restrict__ out) {
    int s0 = blockIdx.x * 8;
    int tid = threadIdx.x;
    __shared__ __align__(16) float vt[8][96];
    __shared__ __align__(16) float gt[8][96];
    __shared__ float mss[8], rss[8];
#pragma unroll
    for (int j = 0; j < 4; j++) {
        int f = tid + j * 192;           // < 768
        int sr = f / 96, c = f % 96;
        const _Float16* yr = ysh + ((size_t)(s0 + sr) * KDIR) * 96 + c;
        float v = 0.f;
#pragma unroll
        for (int k = 0; k < KDIR; k++) v += (float)yr[k * 96];
        vt[sr][c] = v;
    }
    __syncthreads();
    int wave = tid >> 6, lane = tid & 63;
    for (int r = wave; r < 8; r += 3) {
        float v = vt[r][lane] + ((lane < 32) ? vt[r][64 + lane] : 0.f);
#pragma unroll
        for (int off = 1; off < 64; off <<= 1) v += __shfl_xor(v, off);
        float vs = vt[r][lane] * vt[r][lane] + ((lane < 32) ? vt[r][64 + lane] * vt[r][64 + lane] : 0.f);
#pragma unroll
        for (int off = 1; off < 64; off <<= 1) vs += __shfl_xor(vs, off);
        if (lane == 0) {
            float mean = v * (1.f / 96.f);
            float var = vs * (1.f / 96.f) - mean * mean;
            mss[r] = mean; rss[r] = rsqrtf(var + 1e-5f);
        }
    }
    __syncthreads();
#pragma unroll
    for (int j = 0; j < 4; j++) {
        int f = tid + j * 192;
        int sr = f / 96, c = f % 96;
        float g = (vt[sr][c] - mss[sr]) * rss[sr] * onw[c] + onb[c];
        gt[sr][c] = g * (float)zsh[(size_t)(s0 + sr) * 96 + c];
    }
    int e = tid % 96, sg = tid / 96;  // sg in {0,1}
    float4 Wr[24];
    const float4* wr = (const float4*)(Wo + (size_t)e * 96);
#pragma unroll
    for (int c4 = 0; c4 < 24; c4++) Wr[c4] = wr[c4];
    __syncthreads();
#pragma unroll
    for (int j = 0; j < 4; j++) {
        int s = sg * 4 + j;
        const float4* g4 = (const float4*)&gt[s][0];
        float a0 = 0.f, a1 = 0.f, a2 = 0.f, a3 = 0.f;
#pragma unroll
        for (int c4 = 0; c4 < 24; c4 += 4) {
            float4 x0 = g4[c4], x1 = g4[c4 + 1], x2 = g4[c4 + 2], x3 = g4[c4 + 3];
            a0 += Wr[c4].x * x0.x + Wr[c4].y * x0.y + Wr[c4].z * x0.z + Wr[c4].w * x0.w;
            a1 += Wr[c4+1].x * x1.x + Wr[c4+1].y * x1.y + Wr[c4+1].z * x1.z + Wr[c4+1].w * x1.w;
            a2 += Wr[c4+2].x * x2.x + Wr[c4+2].y * x2.y + Wr[c4+2].z * x2.z + Wr[c4+2].w * x2.w;
            a3 += Wr[c4+3].x * x3.x + Wr[c4+3].y * x3.y + Wr[c4+3].z * x3.z + Wr[c4+3].w * x3.w;
        }
        float acc = (a0 + a1) + (a2 + a3) + x[(size_t)(s0 + s) * 96 + e];
        out[(size_t)(s0 + s) * 96 + e] = acc;
    }
}

extern "C" void kernel_launch(void* const* d_in, const int* in_sizes, int n_in,
                              void* d_out, int out_size, void* d_ws, size_t ws_size,
                              hipStream_t stream) {
    const float* x        = (const float*)d_in[0];
    const float* ln1_w    = (const float*)d_in[1];
    const float* ln1_b    = (const float*)d_in[2];
    const float* in_proj  = (const float*)d_in[3];
    const float* conv_w   = (const float*)d_in[4];
    const float* conv_b   = (const float*)d_in[5];
    const float* x_proj   = (const float*)d_in[6];
    const float* dt_w     = (const float*)d_in[7];
    const float* dt_b     = (const float*)d_in[8];
    const float* A_log    = (const float*)d_in[9];
    const float* D_skip   = (const float*)d_in[10];
    const float* onw      = (const float*)d_in[11];
    const float* onb      = (const float*)d_in[12];
    const float* out_w    = (const float*)d_in[13];
    float* out = (float*)d_out;

    _Float16* xhh  = (_Float16*)d_ws;                 // 96*4096
    _Float16* zsh  = xhh + (size_t)96 * L;            // 4096*96
    _Float16* xch  = zsh + (size_t)96 * L;            // 96*4096
    _Float16* xcTh = xch + (size_t)96 * L;            // 4096*96
    _Float16* Y2h  = xcTh + (size_t)96 * L;           // 6*4096*32
    _Float16* Zsh  = Y2h + (size_t)KDIR * L * YH;     // 6*4096*96
    _Float16* ysh  = Zsh + (size_t)KDIR * L * 96;     // 4096*6*96

    k1_ln_inproj<<<dim3(L / 8), dim3(192), 0, stream>>>(x, ln1_w, ln1_b, in_proj, xhh, zsh);
    k2_conv<<<dim3(96 * L / 256), dim3(256), 0, stream>>>(xhh, conv_w, conv_b, xch, xcTh);
    k3_xproj<<<dim3(KDIR, 16, 4), dim3(256), 0, stream>>>(xch, x_proj, dt_w, dt_b, Y2h, Zsh);
    kscan<<<dim3(KDIR * DDIM), dim3(256), 0, stream>>>(Zsh, xcTh, Y2h, A_log, D_skip, ysh);
    k6_out<<<dim3(L / 8), dim3(192), 0, stream>>>(ysh, zsh, onw, onb, out_w, x, out);
}

// Round 3
// 184.716 us; speedup vs baseline: 2.8770x; 1.1381x over previous
//
#include <hip/hip_runtime.h>
#include <hip/hip_bf16.h>

// Sizes (fixed): B=1, D=H=W=16 -> L=4096, C=96, d=96, K=6, N=16, R=6
#define L 4096
#define CDIM 96
#define DDIM 96
#define KDIR 6
#define NST 16
#define RRK 6
#define YH 32        // Yl row: B at [0..15], C at [16..31] (half)
#define NCHUNK 256
#define CHLEN 16     // NCHUNK*CHLEN == L

typedef _Float16 half4v __attribute__((ext_vector_type(4)));

__device__ __forceinline__ float sigmoidf_(float x) { return 1.f / (1.f + __expf(-x)); }

// scan-position l -> spatial index s for base direction kb in {0,1,2}
__device__ __forceinline__ int sigma_k(int kb, int l) {
    if (kb == 0) return l;
    if (kb == 1) return ((l & 15) << 8) | ((l >> 8) << 4) | ((l >> 4) & 15);
    return (((l >> 4) & 15) << 8) | ((l & 15) << 4) | (l >> 8);
}

// spatial s -> scan row l for direction k (sigma_1 and sigma_2 are mutual inverses)
__device__ __forceinline__ int lrow_k(int k, int s) {
    int kb = (k < 3) ? k : (k - 3);
    int l;
    if (kb == 0) l = s;
    else if (kb == 1) l = sigma_k(2, s);   // sigma_1^{-1} = sigma_2
    else l = sigma_k(1, s);                // sigma_2^{-1} = sigma_1
    return (k >= 3) ? (4095 - l) : l;
}

// K1: LN + in_proj, weight-in-registers, 8 spatial rows per block.
__global__ void __launch_bounds__(192) k1_ln_inproj(
        const float* __restrict__ x, const float* __restrict__ ln_w,
        const float* __restrict__ ln_b, const float* __restrict__ Wp,
        _Float16* __restrict__ xhh, _Float16* __restrict__ zsh) {
    int s0 = blockIdx.x * 8;
    int tid = threadIdx.x;
    __shared__ __align__(16) float xt[8][96];
    __shared__ __align__(16) float xn[8][96];
    __shared__ float mss[8], rss[8];
    ((float4*)&xt[0][0])[tid] = ((const float4*)(x + (size_t)s0 * 96))[tid];
    __syncthreads();
    int wave = tid >> 6, lane = tid & 63;
    for (int r = wave; r < 8; r += 3) {
        float v = xt[r][lane] + ((lane < 32) ? xt[r][64 + lane] : 0.f);
#pragma unroll
        for (int off = 1; off < 64; off <<= 1) v += __shfl_xor(v, off);
        float vs = xt[r][lane] * xt[r][lane] + ((lane < 32) ? xt[r][64 + lane] * xt[r][64 + lane] : 0.f);
#pragma unroll
        for (int off = 1; off < 64; off <<= 1) vs += __shfl_xor(vs, off);
        if (lane == 0) {
            float mean = v * (1.f / 96.f);
            float var = vs * (1.f / 96.f) - mean * mean;
            mss[r] = mean; rss[r] = rsqrtf(var + 1e-6f);
        }
    }
    __syncthreads();
    {
        int r = tid / 24, c4 = tid % 24;
        float4 xv = ((float4*)&xt[r][0])[c4];
        float4 wv = ((const float4*)ln_w)[c4];
        float4 bv = ((const float4*)ln_b)[c4];
        float m = mss[r], rs = rss[r];
        float4 o;
        o.x = (xv.x - m) * rs * wv.x + bv.x;
        o.y = (xv.y - m) * rs * wv.y + bv.y;
        o.z = (xv.z - m) * rs * wv.z + bv.z;
        o.w = (xv.w - m) * rs * wv.w + bv.w;
        ((float4*)&xn[r][0])[c4] = o;
    }
    float4 Wr[24];
    const float4* wr = (const float4*)(Wp + (size_t)tid * 96);
#pragma unroll
    for (int c4 = 0; c4 < 24; c4++) Wr[c4] = wr[c4];
    __syncthreads();
#pragma unroll
    for (int s = 0; s < 8; s++) {
        const float4* xr4 = (const float4*)&xn[s][0];
        float a0 = 0.f, a1 = 0.f, a2 = 0.f, a3 = 0.f;
#pragma unroll
        for (int c4 = 0; c4 < 24; c4 += 4) {
            float4 x0 = xr4[c4], x1 = xr4[c4 + 1], x2 = xr4[c4 + 2], x3 = xr4[c4 + 3];
            a0 += Wr[c4].x * x0.x + Wr[c4].y * x0.y + Wr[c4].z * x0.z + Wr[c4].w * x0.w;
            a1 += Wr[c4+1].x * x1.x + Wr[c4+1].y * x1.y + Wr[c4+1].z * x1.z + Wr[c4+1].w * x1.w;
            a2 += Wr[c4+2].x * x2.x + Wr[c4+2].y * x2.y + Wr[c4+2].z * x2.z + Wr[c4+2].w * x2.w;
            a3 += Wr[c4+3].x * x3.x + Wr[c4+3].y * x3.y + Wr[c4+3].z * x3.z + Wr[c4+3].w * x3.w;
        }
        float acc = (a0 + a1) + (a2 + a3);
        if (tid < 96) xhh[(size_t)tid * L + s0 + s] = (_Float16)acc;
        else zsh[(size_t)(s0 + s) * 96 + (tid - 96)] = (_Float16)(acc * sigmoidf_(acc));
    }
}

// K2: depthwise 3x3x3 conv (SAME) + bias + SiLU; writes xch[c][s] and xcTh[s][c]
__global__ void k2_conv(const _Float16* __restrict__ xhh, const float* __restrict__ cw,
                        const float* __restrict__ cb, _Float16* __restrict__ xch,
                        _Float16* __restrict__ xcTh) {
    int idx = blockIdx.x * 256 + threadIdx.x; // 96*4096
    int c = idx >> 12, s = idx & 4095;
    int dz = s >> 8, h = (s >> 4) & 15, w = s & 15;
    const _Float16* xin = xhh + (size_t)c * L;
    const float* wc = cw + c * 27;
    float acc = cb[c];
#pragma unroll
    for (int i = 0; i < 3; i++) {
        int z2 = dz + i - 1; if ((unsigned)z2 > 15u) continue;
#pragma unroll
        for (int j = 0; j < 3; j++) {
            int h2 = h + j - 1; if ((unsigned)h2 > 15u) continue;
#pragma unroll
            for (int kk = 0; kk < 3; kk++) {
                int w2 = w + kk - 1; if ((unsigned)w2 > 15u) continue;
                acc += (float)xin[z2 * 256 + h2 * 16 + w2] * wc[i * 9 + j * 3 + kk];
            }
        }
    }
    float r = acc * sigmoidf_(acc);
    _Float16 hr = (_Float16)r;
    xch[(size_t)c * L + s] = hr;
    xcTh[(size_t)s * 96 + c] = hr;
}

// K3: x_proj + dt expand + softplus. Writes all scan-side arrays IN SCAN ORDER
// per direction k (row l = lrow_k(k,s)), and precomputes dtx = dt*xc.
// grid (6,16,4): group g computes 6 dt channels (redundant) + 8 B/C channels,
// then expands dt -> Zl/dtxl for its 24-of-96 d-range.
__global__ void k3_xproj(const _Float16* __restrict__ xch, const float* __restrict__ Wx,
                         const float* __restrict__ Wdt, const float* __restrict__ bdt,
                         _Float16* __restrict__ Yl, _Float16* __restrict__ Zl,
                         _Float16* __restrict__ dtxl) {
    int k = blockIdx.x;
    int tid = threadIdx.x;
    int sbase = blockIdx.y * 256;
    int s = sbase + tid;
    int g = blockIdx.z;   // 0..3
    __shared__ float dts[256][6];
    __shared__ _Float16 xcs[96][258];   // +2 pad: conflict-free column reads
    float acc[14];
#pragma unroll
    for (int i = 0; i < 14; i++) acc[i] = 0.f;
    const float* wdt_rows = Wx + (size_t)k * 38 * DDIM;                 // channels 0..5
    const float* wbc      = Wx + ((size_t)k * 38 + 6 + g * 8) * DDIM;   // 8 B/C channels
    for (int dd = 0; dd < 96; dd += 4) {
        float v[4];
#pragma unroll
        for (int j = 0; j < 4; j++) {
            _Float16 hv = xch[(size_t)(dd + j) * L + s];
            v[j] = (float)hv;
            xcs[dd + j][tid] = hv;
        }
#pragma unroll
        for (int j = 0; j < 4; j++) {
#pragma unroll
            for (int r = 0; r < 6; r++) acc[r] += wdt_rows[r * DDIM + dd + j] * v[j];
#pragma unroll
            for (int i = 0; i < 8; i++) acc[6 + i] += wbc[i * DDIM + dd + j] * v[j];
        }
    }
    {
        int lr = lrow_k(k, s);
        _Float16* yo = Yl + ((size_t)k * L + lr) * YH;
#pragma unroll
        for (int i = 0; i < 8; i++) yo[g * 8 + i] = (_Float16)acc[6 + i];
    }
#pragma unroll
    for (int r = 0; r < 6; r++) dts[tid][r] = acc[r];
    __syncthreads();
    for (int i = 0; i < 24; i++) {
        int idx = i * 256 + tid;      // < 6144 = 256 sr * 24 dl
        int dl = idx % 24;
        int sr = idx / 24;
        int d = g * 24 + dl;
        const float* wr = Wdt + ((size_t)k * 96 + d) * 6;
        float a = bdt[k * 96 + d];
#pragma unroll
        for (int r = 0; r < 6; r++) a += wr[r] * dts[sr][r];
        float sp = (a > 15.f) ? a : __logf(1.f + __expf(a));
        int lr = lrow_k(k, sbase + sr);
        size_t o = ((size_t)k * L + lr) * 96 + d;
        Zl[o] = (_Float16)sp;
        dtxl[o] = (_Float16)(sp * (float)xcs[d][sr]);
    }
}

// KA: chunk-local scan. Pure sequential streams (scan-order arrays), d-coalesced
// thread map: wave = 16 d x 4 nq, fixed chunk.
__global__ void __launch_bounds__(256) ka_scan(
        const _Float16* __restrict__ Zl, const _Float16* __restrict__ dtxl,
        const _Float16* __restrict__ Yl, const float* __restrict__ A_log,
        _Float16* __restrict__ Aah, _Float16* __restrict__ Abh) {
    int t = blockIdx.x * 256 + threadIdx.x;
    int nq = t & 3;
    int q = t >> 2;
    int d = q % 96;
    int rest = q / 96;
    int chunk = rest % NCHUNK;
    int k = rest / NCHUNK;
    float An[4];
    {
        float4 al = *(const float4*)(A_log + ((size_t)k * 96 + d) * 16 + nq * 4);
        An[0] = -__expf(al.x) * 1.44269504f; An[1] = -__expf(al.y) * 1.44269504f;
        An[2] = -__expf(al.z) * 1.44269504f; An[3] = -__expf(al.w) * 1.44269504f;
    }
    float a[4] = {1.f, 1.f, 1.f, 1.f};
    float b[4] = {0.f, 0.f, 0.f, 0.f};
    const _Float16* Zk = Zl + (size_t)k * L * 96;
    const _Float16* Xk = dtxl + (size_t)k * L * 96;
    const _Float16* Yk = Yl + (size_t)k * L * YH;
    int l0 = chunk * CHLEN;
    for (int i = 0; i < CHLEN; i += 4) {
        float dt[4], dx[4]; half4v Bh[4];
#pragma unroll
        for (int j = 0; j < 4; j++) {
            int l = l0 + i + j;
            dt[j] = (float)Zk[(size_t)l * 96 + d];
            dx[j] = (float)Xk[(size_t)l * 96 + d];
            Bh[j] = *(const half4v*)(Yk + (size_t)l * YH + nq * 4);
        }
#pragma unroll
        for (int j = 0; j < 4; j++) {
            float e0 = exp2f(dt[j] * An[0]);
            float e1 = exp2f(dt[j] * An[1]);
            float e2 = exp2f(dt[j] * An[2]);
            float e3 = exp2f(dt[j] * An[3]);
            b[0] = e0 * b[0] + dx[j] * (float)Bh[j].x; a[0] *= e0;
            b[1] = e1 * b[1] + dx[j] * (float)Bh[j].y; a[1] *= e1;
            b[2] = e2 * b[2] + dx[j] * (float)Bh[j].z; a[2] *= e2;
            b[3] = e3 * b[3] + dx[j] * (float)Bh[j].w; a[3] *= e3;
        }
    }
    size_t o = (((size_t)k * NCHUNK + chunk) * 96 + d) * 16 + nq * 4;
    half4v ha, hb;
    ha.x = (_Float16)a[0]; ha.y = (_Float16)a[1]; ha.z = (_Float16)a[2]; ha.w = (_Float16)a[3];
    hb.x = (_Float16)b[0]; hb.y = (_Float16)b[1]; hb.z = (_Float16)b[2]; hb.w = (_Float16)b[3];
    *(half4v*)(Aah + o) = ha;
    *(half4v*)(Abh + o) = hb;
}

// KB: serial combine across 256 chunks per (k,d,n); fp16 in/out (unchanged)
__global__ void __launch_bounds__(256) kb_combine(
        const _Float16* __restrict__ Aah, const _Float16* __restrict__ Abh,
        _Float16* __restrict__ Pbh) {
    int t = blockIdx.x * 256 + threadIdx.x;  // < 6*96*16 = 9216
    int n = t & 15;
    int rest = t >> 4;
    int d = rest % 96;
    int k = rest / 96;
    size_t base = ((size_t)k * NCHUNK * 96 + d) * 16 + n;
    const size_t cstride = 96 * 16;
    float rb = 0.f;
    for (int c0 = 0; c0 < NCHUNK; c0 += 16) {
        float av[16], bv[16];
#pragma unroll
        for (int j = 0; j < 16; j++) {
            av[j] = (float)Aah[base + (size_t)(c0 + j) * cstride];
            bv[j] = (float)Abh[base + (size_t)(c0 + j) * cstride];
        }
#pragma unroll
        for (int j = 0; j < 16; j++) {
            Pbh[base + (size_t)(c0 + j) * cstride] = (_Float16)rb;
            rb = av[j] * rb + bv[j];
        }
    }
}

// KC: re-scan with carry, fuse y = sum_n h*C (D-skip moved to k6); write spatial
__global__ void __launch_bounds__(256) kc_apply(
        const _Float16* __restrict__ Zl, const _Float16* __restrict__ dtxl,
        const _Float16* __restrict__ Yl, const float* __restrict__ A_log,
        const _Float16* __restrict__ Pbh, _Float16* __restrict__ ysh) {
    int t = blockIdx.x * 256 + threadIdx.x;
    int nq = t & 3;
    int q = t >> 2;
    int d = q % 96;
    int rest = q / 96;
    int chunk = rest % NCHUNK;
    int k = rest / NCHUNK;
    int kb = (k < 3) ? k : (k - 3);
    bool flip = (k >= 3);
    float An[4];
    {
        float4 al = *(const float4*)(A_log + ((size_t)k * 96 + d) * 16 + nq * 4);
        An[0] = -__expf(al.x) * 1.44269504f; An[1] = -__expf(al.y) * 1.44269504f;
        An[2] = -__expf(al.z) * 1.44269504f; An[3] = -__expf(al.w) * 1.44269504f;
    }
    float h[4];
    {
        half4v hp = *(const half4v*)(Pbh + (((size_t)k * NCHUNK + chunk) * 96 + d) * 16 + nq * 4);
        h[0] = (float)hp.x; h[1] = (float)hp.y; h[2] = (float)hp.z; h[3] = (float)hp.w;
    }
    const _Float16* Zk = Zl + (size_t)k * L * 96;
    const _Float16* Xk = dtxl + (size_t)k * L * 96;
    const _Float16* Yk = Yl + (size_t)k * L * YH;
    int l0 = chunk * CHLEN;
    for (int i = 0; i < CHLEN; i += 4) {
        float dt[4], dx[4]; half4v Bh[4], Ch[4];
#pragma unroll
        for (int j = 0; j < 4; j++) {
            int l = l0 + i + j;
            dt[j] = (float)Zk[(size_t)l * 96 + d];
            dx[j] = (float)Xk[(size_t)l * 96 + d];
            Bh[j] = *(const half4v*)(Yk + (size_t)l * YH + nq * 4);
            Ch[j] = *(const half4v*)(Yk + (size_t)l * YH + 16 + nq * 4);
        }
#pragma unroll
        for (int j = 0; j < 4; j++) {
            int l = l0 + i + j;
            float e0 = exp2f(dt[j] * An[0]);
            float e1 = exp2f(dt[j] * An[1]);
            float e2 = exp2f(dt[j] * An[2]);
            float e3 = exp2f(dt[j] * An[3]);
            h[0] = e0 * h[0] + dx[j] * (float)Bh[j].x;
            h[1] = e1 * h[1] + dx[j] * (float)Bh[j].y;
            h[2] = e2 * h[2] + dx[j] * (float)Bh[j].z;
            h[3] = e3 * h[3] + dx[j] * (float)Bh[j].w;
            float p = h[0] * (float)Ch[j].x + h[1] * (float)Ch[j].y
                    + h[2] * (float)Ch[j].z + h[3] * (float)Ch[j].w;
            p += __shfl_xor(p, 1);
            p += __shfl_xor(p, 2);
            if (nq == 0) {
                int lp = flip ? (4095 - l) : l;
                int sI = sigma_k(kb, lp);
                ysh[((size_t)sI * KDIR + k) * 96 + d] = (_Float16)p;
            }
        }
    }
}

// K6: k-sum + Dsum*xc + out LN + z gate + out_proj + residual
__global__ void __launch_bounds__(192) k6_out(
        const _Float16* __restrict__ ysh, const _Float16* __restrict__ zsh,
        const _Float16* __restrict__ xcTh, const float* __restrict__ D_skip,
        const float* __restrict__ onw, const float* __restrict__ onb,
        const float* __restrict__ Wo, const float* __restrict__ x,
        float* __restrict__ out) {
    int s0 = blockIdx.x * 8;
    int tid = threadIdx.x;
    __shared__ __align__(16) float vt[8][96];
    __shared__ __align__(16) float gt[8][96];
    __shared__ float mss[8], rss[8];
#pragma unroll
    for (int j = 0; j < 4; j++) {
        int f = tid + j * 192;           // < 768
        int sr = f / 96, c = f % 96;
        const _Float16* yr = ysh + ((size_t)(s0 + sr) * KDIR) * 96 + c;
        float v = 0.f;
#pragma unroll
        for (int k = 0; k < KDIR; k++) v += (float)yr[k * 96];
        float ds = 0.f;
#pragma unroll
        for (int k = 0; k < KDIR; k++) ds += D_skip[k * DDIM + c];
        v += ds * (float)xcTh[(size_t)(s0 + sr) * 96 + c];
        vt[sr][c] = v;
    }
    __syncthreads();
    int wave = tid >> 6, lane = tid & 63;
    for (int r = wave; r < 8; r += 3) {
        float v = vt[r][lane] + ((lane < 32) ? vt[r][64 + lane] : 0.f);
#pragma unroll
        for (int off = 1; off < 64; off <<= 1) v += __shfl_xor(v, off);
        float vs = vt[r][lane] * vt[r][lane] + ((lane < 32) ? vt[r][64 + lane] * vt[r][64 + lane] : 0.f);
#pragma unroll
        for (int off = 1; off < 64; off <<= 1) vs += __shfl_xor(vs, off);
        if (lane == 0) {
            float mean = v * (1.f / 96.f);
            float var = vs * (1.f / 96.f) - mean * mean;
            mss[r] = mean; rss[r] = rsqrtf(var + 1e-5f);
        }
    }
    __syncthreads();
#pragma unroll
    for (int j = 0; j < 4; j++) {
        int f = tid + j * 192;
        int sr = f / 96, c = f % 96;
        float g = (vt[sr][c] - mss[sr]) * rss[sr] * onw[c] + onb[c];
        gt[sr][c] = g * (float)zsh[(size_t)(s0 + sr) * 96 + c];
    }
    int e = tid % 96, sg = tid / 96;  // sg in {0,1}
    float4 Wr[24];
    const float4* wr = (const float4*)(Wo + (size_t)e * 96);
#pragma unroll
    for (int c4 = 0; c4 < 24; c4++) Wr[c4] = wr[c4];
    __syncthreads();
#pragma unroll
    for (int j = 0; j < 4; j++) {
        int s = sg * 4 + j;
        const float4* g4 = (const float4*)&gt[s][0];
        float a0 = 0.f, a1 = 0.f, a2 = 0.f, a3 = 0.f;
#pragma unroll
        for (int c4 = 0; c4 < 24; c4 += 4) {
            float4 x0 = g4[c4], x1 = g4[c4 + 1], x2 = g4[c4 + 2], x3 = g4[c4 + 3];
            a0 += Wr[c4].x * x0.x + Wr[c4].y * x0.y + Wr[c4].z * x0.z + Wr[c4].w * x0.w;
            a1 += Wr[c4+1].x * x1.x + Wr[c4+1].y * x1.y + Wr[c4+1].z * x1.z + Wr[c4+1].w * x1.w;
            a2 += Wr[c4+2].x * x2.x + Wr[c4+2].y * x2.y + Wr[c4+2].z * x2.z + Wr[c4+2].w * x2.w;
            a3 += Wr[c4+3].x * x3.x + Wr[c4+3].y * x3.y + Wr[c4+3].z * x3.z + Wr[c4+3].w * x3.w;
        }
        float acc = (a0 + a1) + (a2 + a3) + x[(size_t)(s0 + s) * 96 + e];
        out[(size_t)(s0 + s) * 96 + e] = acc;
    }
}

extern "C" void kernel_launch(void* const* d_in, const int* in_sizes, int n_in,
                              void* d_out, int out_size, void* d_ws, size_t ws_size,
                              hipStream_t stream) {
    const float* x        = (const float*)d_in[0];
    const float* ln1_w    = (const float*)d_in[1];
    const float* ln1_b    = (const float*)d_in[2];
    const float* in_proj  = (const float*)d_in[3];
    const float* conv_w   = (const float*)d_in[4];
    const float* conv_b   = (const float*)d_in[5];
    const float* x_proj   = (const float*)d_in[6];
    const float* dt_w     = (const float*)d_in[7];
    const float* dt_b     = (const float*)d_in[8];
    const float* A_log    = (const float*)d_in[9];
    const float* D_skip   = (const float*)d_in[10];
    const float* onw      = (const float*)d_in[11];
    const float* onb      = (const float*)d_in[12];
    const float* out_w    = (const float*)d_in[13];
    float* out = (float*)d_out;

    _Float16* xhh  = (_Float16*)d_ws;                 // 96*4096
    _Float16* zsh  = xhh + (size_t)96 * L;            // 4096*96
    _Float16* xch  = zsh + (size_t)96 * L;            // 96*4096
    _Float16* xcTh = xch + (size_t)96 * L;            // 4096*96
    _Float16* Yl   = xcTh + (size_t)96 * L;           // 6*4096*32  (scan order)
    _Float16* Zl   = Yl + (size_t)KDIR * L * YH;      // 6*4096*96  (scan order)
    _Float16* dtxl = Zl + (size_t)KDIR * L * 96;      // 6*4096*96  (scan order)
    _Float16* ysh  = dtxl + (size_t)KDIR * L * 96;    // 4096*6*96  (spatial)
    _Float16* Aah  = ysh + (size_t)L * KDIR * 96;     // 6*256*96*16
    _Float16* Abh  = Aah + (size_t)KDIR * NCHUNK * DDIM * NST;
    _Float16* Pbh  = Abh + (size_t)KDIR * NCHUNK * DDIM * NST;

    k1_ln_inproj<<<dim3(L / 8), dim3(192), 0, stream>>>(x, ln1_w, ln1_b, in_proj, xhh, zsh);
    k2_conv<<<dim3(96 * L / 256), dim3(256), 0, stream>>>(xhh, conv_w, conv_b, xch, xcTh);
    k3_xproj<<<dim3(KDIR, 16, 4), dim3(256), 0, stream>>>(xch, x_proj, dt_w, dt_b, Yl, Zl, dtxl);
    ka_scan<<<dim3(KDIR * NCHUNK * DDIM * 4 / 256), dim3(256), 0, stream>>>(Zl, dtxl, Yl, A_log, Aah, Abh);
    kb_combine<<<dim3(KDIR * DDIM * NST / 256), dim3(256), 0, stream>>>(Aah, Abh, Pbh);
    kc_apply<<<dim3(KDIR * NCHUNK * DDIM * 4 / 256), dim3(256), 0, stream>>>(Zl, dtxl, Yl, A_log, Pbh, ysh);
    k6_out<<<dim3(L / 8), dim3(192), 0, stream>>>(ysh, zsh, xcTh, D_skip, onw, onb, out_w, x, out);
}